// Round 2
// baseline (272.555 us; speedup 1.0000x reference)
//
#include <hip/hip_runtime.h>

#define BN 100000
#define DD 128
#define EN 500000
#define NM 4096
#define NROWS (BN + NM)     // 104096
#define MT 128              // gemm row tile
#define XLP 132             // padded leading dim for XlT (breaks 8-way conflicts)
#define GEMM_NB ((NROWS + MT - 1) / MT)   // 814 gemm blocks
#define HIST_NB ((EN / 4 + 255) / 256)    // 489 hist blocks

// ---- ws layout (4-byte units) ----
#define OFF_H      0
#define LEN_H      ((size_t)NROWS * DD)           // 13,324,288
#define OFF_CNT    (LEN_H)                        // 100000 ints  (memset 0)
#define OFF_SLOTS  (OFF_CNT + BN)                 // 256 f xbnorm (memset 0)
#define OFF_ISLOTS (OFF_SLOTS + 256)              // 256 f info   (memset 0)
#define OFF_RS     (OFF_ISLOTS + 256)             // 100001 ints
#define OFF_NEXT   (OFF_RS + BN + 1)              // 100000 ints
#define OFF_EQ     ((OFF_NEXT + BN + 1) & ~(size_t)1)  // int2[EN], 8B-aligned
#define OFF_BS     (OFF_EQ + 2 * (size_t)EN)      // 128 ints

// ---------------- GEMM: h = [X_B; codebook*warm] @ W  (+ fused xb_norm)
// ---------------- + fused dst-histogram in tail blocks (data-independent).
// Blocks [0, GEMM_NB): gemm tile.  Blocks [GEMM_NB, GEMM_NB+HIST_NB): hist.
// Hist blocks fill the gemm tail (814 blocks = 1 residency wave + 46-block
// tail at ~3 blocks/CU), hiding hist's atomics under gemm compute.
__launch_bounds__(256)
__global__ void k_gemm(const float* __restrict__ X_B, const float* __restrict__ codebook,
                       const float* __restrict__ W, const float* __restrict__ warm,
                       float* __restrict__ h, float* __restrict__ slots,
                       const int* __restrict__ edge_dst, int* __restrict__ cnt) {
    if (blockIdx.x >= GEMM_NB) {
        // ---- histogram by dst (int4), block-uniform branch, no barriers ----
        const int e4 = (blockIdx.x - GEMM_NB) * 256 + threadIdx.x;
        if (e4 < EN / 4) {
            const int4 d = ((const int4*)edge_dst)[e4];
            atomicAdd(&cnt[d.x], 1);
            atomicAdd(&cnt[d.y], 1);
            atomicAdd(&cnt[d.z], 1);
            atomicAdd(&cnt[d.w], 1);
        }
        return;
    }

    __shared__ __align__(16) float XlT[32 * XLP];   // [k][r], padded
    __shared__ __align__(16) float Wl[32 * 128];    // [k][c]
    const int tid = threadIdx.x;
    const int tx = tid & 15, ty = tid >> 4;
    const int r0 = blockIdx.x * MT;
    const float wu = *warm;

    float acc[8][8];
#pragma unroll
    for (int i = 0; i < 8; i++)
#pragma unroll
        for (int j = 0; j < 8; j++) acc[i][j] = 0.f;

    float part[4] = {0.f, 0.f, 0.f, 0.f};   // xb_norm partials (row = (i*256+tid)>>3)

    const float4* xb4 = (const float4*)X_B;
    const float4* cb4 = (const float4*)codebook;
    const float4* W4 = (const float4*)W;

    for (int kc = 0; kc < 4; kc++) {
        __syncthreads();
#pragma unroll
        for (int i = 0; i < 4; i++) {
            const int f = i * 256 + tid;
            const int r = f >> 3, kq = f & 7;
            const int R = r0 + r;
            float4 v = make_float4(0.f, 0.f, 0.f, 0.f);
            if (R < NROWS) {
                if (R < BN) {
                    v = xb4[(size_t)R * 32 + kc * 8 + kq];
                    part[i] += v.x * v.x + v.y * v.y + v.z * v.z + v.w * v.w;
                } else {
                    v = cb4[(size_t)(R - BN) * 32 + kc * 8 + kq];
                    v.x *= wu; v.y *= wu; v.z *= wu; v.w *= wu;
                }
            }
            XlT[(kq * 4 + 0) * XLP + r] = v.x;
            XlT[(kq * 4 + 1) * XLP + r] = v.y;
            XlT[(kq * 4 + 2) * XLP + r] = v.z;
            XlT[(kq * 4 + 3) * XLP + r] = v.w;
        }
#pragma unroll
        for (int i = 0; i < 4; i++) {
            const int f = i * 256 + tid;
            ((float4*)Wl)[f] = W4[kc * 1024 + f];
        }
        __syncthreads();
#pragma unroll 4
        for (int k = 0; k < 32; k++) {
            const float4 a0 = *(const float4*)&XlT[k * XLP + ty * 4];
            const float4 a1 = *(const float4*)&XlT[k * XLP + 64 + ty * 4];
            const float4 b0 = *(const float4*)&Wl[k * 128 + tx * 4];
            const float4 b1 = *(const float4*)&Wl[k * 128 + 64 + tx * 4];
            const float ar[8] = {a0.x, a0.y, a0.z, a0.w, a1.x, a1.y, a1.z, a1.w};
            const float bc[8] = {b0.x, b0.y, b0.z, b0.w, b1.x, b1.y, b1.z, b1.w};
#pragma unroll
            for (int i = 0; i < 8; i++)
#pragma unroll
                for (int j = 0; j < 8; j++) acc[i][j] += ar[i] * bc[j];
        }
    }
#pragma unroll
    for (int i = 0; i < 8; i++) {
        const int R = r0 + ((i < 4) ? (ty * 4 + i) : (64 + ty * 4 + i - 4));
        if (R < NROWS) {
            float4 o0 = make_float4(acc[i][0], acc[i][1], acc[i][2], acc[i][3]);
            float4 o1 = make_float4(acc[i][4], acc[i][5], acc[i][6], acc[i][7]);
            *(float4*)&h[(size_t)R * DD + tx * 4] = o0;
            *(float4*)&h[(size_t)R * DD + 64 + tx * 4] = o1;
        }
    }
    // xb_norm: sum part over the 8 kq-lanes of each row (segmented shfl_xor),
    // sqrt on kq==0 lane, then block reduce -> 1 atomic per wave.
    float local = 0.f;
#pragma unroll
    for (int i = 0; i < 4; i++) {
        float p = part[i];
        p += __shfl_xor(p, 1);
        p += __shfl_xor(p, 2);
        p += __shfl_xor(p, 4);
        const int R = r0 + ((i * 256 + tid) >> 3);
        if ((tid & 7) == 0 && R < BN) local += sqrtf(p);
    }
#pragma unroll
    for (int off = 32; off > 0; off >>= 1) local += __shfl_down(local, off);
    if ((tid & 63) == 0) unsafeAtomicAdd(&slots[blockIdx.x & 255], local);
}

// ---------------- scan phase 1 ----------------
__launch_bounds__(1024)
__global__ void k_scan1(const int* __restrict__ cnt, int* __restrict__ rs,
                        int* __restrict__ bs) {
    __shared__ int sd[1024];
    const int t = threadIdx.x;
    const int i = blockIdx.x * 1024 + t;
    int v = (i < BN) ? cnt[i] : 0;
    sd[t] = v;
    __syncthreads();
    for (int off = 1; off < 1024; off <<= 1) {
        int x = (t >= off) ? sd[t - off] : 0;
        __syncthreads();
        sd[t] += x;
        __syncthreads();
    }
    if (i < BN) rs[i] = sd[t] - v;
    if (t == 0) bs[blockIdx.x] = sd[1023];
}

// ---------------- scan phase 2 ----------------
__global__ void k_scan2(int* __restrict__ bs) {
    __shared__ int sd[128];
    const int t = threadIdx.x;
    int v = (t < 98) ? bs[t] : 0;
    sd[t] = v;
    __syncthreads();
    for (int off = 1; off < 128; off <<= 1) {
        int x = (t >= off) ? sd[t - off] : 0;
        __syncthreads();
        sd[t] += x;
        __syncthreads();
    }
    bs[t] = sd[t] - v;
}

// ---------------- scan phase 3 ----------------
__launch_bounds__(1024)
__global__ void k_scan3(int* __restrict__ rs, int* __restrict__ next,
                        const int* __restrict__ bs) {
    const int i = blockIdx.x * 1024 + threadIdx.x;
    if (i < BN) {
        int v = rs[i] + bs[blockIdx.x];
        rs[i] = v;
        next[i] = v;
    }
    if (i == 0) rs[BN] = EN;
}

// ---------------- slot-scatter edges into CSR order (packed int2) --------
__global__ void k_slot(const int* __restrict__ edge_dst, const int* __restrict__ edge_src,
                       const float* __restrict__ ew, const int* __restrict__ cidx,
                       int* __restrict__ next, int2* __restrict__ eq) {
    for (int e = blockIdx.x * blockDim.x + threadIdx.x; e < EN;
         e += gridDim.x * blockDim.x) {
        const int d = edge_dst[e];
        const int s = edge_src[e];
        const int p = atomicAdd(&next[d], 1);
        const int se = (s < BN) ? s : (BN + cidx[s]);
        eq[p] = make_int2(se, __float_as_int(ew[e]));
    }
}

// ---------------- fused aggregate + info ----------------
__launch_bounds__(256)
__global__ void k_aggregate(const float* __restrict__ h, const int* __restrict__ rs,
                            const int2* __restrict__ eq,
                            const float* __restrict__ b, const float* __restrict__ grad,
                            float* __restrict__ out, float* __restrict__ islots) {
    const int lane = threadIdx.x & 63;
    const int wave = threadIdx.x >> 6;
    const int row = blockIdx.x * 4 + wave;   // grid 25000
    const float2* h2 = (const float2*)h;
    const float2* g2 = (const float2*)grad;

    float myinfo = 0.f;
    {
        const int gid = blockIdx.x * 256 + threadIdx.x;
        if (gid < NM * DD) myinfo = b[gid & 127] * grad[gid];
    }

    const int s0 = rs[row], s1 = rs[row + 1];
    const int cnt = s1 - s0;

    const float2 hd = h2[(size_t)row * 64 + lane];
    float2 acc = ((const float2*)b)[lane];
    int sv = 0; float wv = 0.f;
    if (lane < cnt) {
        const int2 e = eq[s0 + lane];
        sv = e.x; wv = __int_as_float(e.y);
    }

    float2 gacc = make_float2(0.f, 0.f);
    const int nb = (cnt < 64) ? cnt : 64;
    int i = 0;
    for (; i + 4 <= nb; i += 4) {
        const int sr0 = __shfl(sv, i),     sr1 = __shfl(sv, i + 1);
        const int sr2 = __shfl(sv, i + 2), sr3 = __shfl(sv, i + 3);
        const float w0 = __shfl(wv, i),     w1 = __shfl(wv, i + 1);
        const float w2 = __shfl(wv, i + 2), w3 = __shfl(wv, i + 3);
        const float2 h0 = h2[(size_t)sr0 * 64 + lane];
        const float2 h1 = h2[(size_t)sr1 * 64 + lane];
        const float2 hh2 = h2[(size_t)sr2 * 64 + lane];
        const float2 h3 = h2[(size_t)sr3 * 64 + lane];
        const int m0 = sr0 - BN, m1 = sr1 - BN, m2 = sr2 - BN, m3 = sr3 - BN;
        const float2 g0 = g2[(size_t)max(m0, 0) * 64 + lane];
        const float2 g1 = g2[(size_t)max(m1, 0) * 64 + lane];
        const float2 g2v = g2[(size_t)max(m2, 0) * 64 + lane];
        const float2 g3 = g2[(size_t)max(m3, 0) * 64 + lane];
        acc.x += w0 * h0.x + w1 * h1.x + w2 * hh2.x + w3 * h3.x;
        acc.y += w0 * h0.y + w1 * h1.y + w2 * hh2.y + w3 * h3.y;
        const float gw0 = (m0 >= 0) ? w0 : 0.f, gw1 = (m1 >= 0) ? w1 : 0.f;
        const float gw2 = (m2 >= 0) ? w2 : 0.f, gw3 = (m3 >= 0) ? w3 : 0.f;
        gacc.x += gw0 * g0.x + gw1 * g1.x + gw2 * g2v.x + gw3 * g3.x;
        gacc.y += gw0 * g0.y + gw1 * g1.y + gw2 * g2v.y + gw3 * g3.y;
    }
    for (; i < nb; i++) {
        const int sr = __shfl(sv, i);
        const float w = __shfl(wv, i);
        const float2 hv = h2[(size_t)sr * 64 + lane];
        acc.x += w * hv.x; acc.y += w * hv.y;
        const int m = sr - BN;
        const float2 gv = g2[(size_t)max(m, 0) * 64 + lane];
        const float gw = (m >= 0) ? w : 0.f;
        gacc.x += gw * gv.x; gacc.y += gw * gv.y;
    }
    for (int j = s0 + 64; j < s1; j++) {
        const int2 e = eq[j];
        const int sr = e.x; const float w = __int_as_float(e.y);
        const float2 hv = h2[(size_t)sr * 64 + lane];
        acc.x += w * hv.x; acc.y += w * hv.y;
        const int m = sr - BN;
        const float2 gv = g2[(size_t)max(m, 0) * 64 + lane];
        const float gw = (m >= 0) ? w : 0.f;
        gacc.x += gw * gv.x; gacc.y += gw * gv.y;
    }

    ((float2*)out)[(size_t)row * 64 + lane] = acc;
    myinfo += hd.x * gacc.x + hd.y * gacc.y;
#pragma unroll
    for (int off = 32; off > 0; off >>= 1) myinfo += __shfl_down(myinfo, off);
    __shared__ float li[4];
    if (lane == 0) li[wave] = myinfo;
    __syncthreads();
    if (threadIdx.x == 0)
        unsafeAtomicAdd(&islots[blockIdx.x & 255], li[0] + li[1] + li[2] + li[3]);
}

// ---------------- finalize scalars ----------------
__global__ void k_finalize(const float* __restrict__ slots, const float* __restrict__ islots,
                           const float* __restrict__ warm, float* __restrict__ out_tail) {
    float v = slots[threadIdx.x];
    float u = islots[threadIdx.x];
#pragma unroll
    for (int off = 32; off > 0; off >>= 1) {
        v += __shfl_down(v, off);
        u += __shfl_down(u, off);
    }
    __shared__ float lv[4], lu[4];
    if ((threadIdx.x & 63) == 0) { lv[threadIdx.x >> 6] = v; lu[threadIdx.x >> 6] = u; }
    __syncthreads();
    if (threadIdx.x == 0) {
        out_tail[0] = (lv[0] + lv[1] + lv[2] + lv[3]) / (float)BN;
        out_tail[1] = (lu[0] + lu[1] + lu[2] + lu[3]) * warm[0];
    }
}

extern "C" void kernel_launch(void* const* d_in, const int* in_sizes, int n_in,
                              void* d_out, int out_size, void* d_ws, size_t ws_size,
                              hipStream_t stream) {
    const float* X_B      = (const float*)d_in[0];
    const int*   edge_dst = (const int*)d_in[1];
    const int*   edge_src = (const int*)d_in[2];
    const float* ew       = (const float*)d_in[3];
    const int*   cidx     = (const int*)d_in[5];
    const float* codebook = (const float*)d_in[6];
    const float* grad     = (const float*)d_in[7];
    const float* W        = (const float*)d_in[8];
    const float* b        = (const float*)d_in[9];
    const float* warm     = (const float*)d_in[10];
    float* out = (float*)d_out;
    float* ws  = (float*)d_ws;

    float* h      = ws + OFF_H;
    int*   cnt    = (int*)(ws + OFF_CNT);
    float* slots  = ws + OFF_SLOTS;
    float* islots = ws + OFF_ISLOTS;
    int*   rs     = (int*)(ws + OFF_RS);
    int*   next   = (int*)(ws + OFF_NEXT);
    int2*  eq     = (int2*)(ws + OFF_EQ);
    int*   bs     = (int*)(ws + OFF_BS);

    hipMemsetAsync(cnt, 0, (BN + 512) * sizeof(float), stream);

    k_gemm<<<GEMM_NB + HIST_NB, 256, 0, stream>>>(X_B, codebook, W, warm, h, slots,
                                                  edge_dst, cnt);
    k_scan1<<<98, 1024, 0, stream>>>(cnt, rs, bs);
    k_scan2<<<1, 128, 0, stream>>>(bs);
    k_scan3<<<98, 1024, 0, stream>>>(rs, next, bs);
    k_slot<<<512, 256, 0, stream>>>(edge_dst, edge_src, ew, cidx, next, eq);
    k_aggregate<<<BN / 4, 256, 0, stream>>>(h, rs, eq, b, grad, out, islots);
    k_finalize<<<1, 256, 0, stream>>>(slots, islots, warm, out + (size_t)BN * DD);
}

// Round 3
// 238.635 us; speedup vs baseline: 1.1421x; 1.1421x over previous
//
#include <hip/hip_runtime.h>

#define BN 100000
#define DD 128
#define EN 500000
#define NM 4096
#define NROWS (BN + NM)     // 104096
#define MT 128              // gemm row tile
#define GEMM_NB ((NROWS + MT - 1) / MT)   // 814 gemm blocks
#define HIST_NB ((EN / 4 + 255) / 256)    // 489 hist blocks

// ---- ws layout (4-byte units) ----
#define OFF_H      0
#define LEN_H      ((size_t)NROWS * DD)           // 13,324,288
#define OFF_CNT    (LEN_H)                        // 100000 ints  (memset 0)
#define OFF_SLOTS  (OFF_CNT + BN)                 // 256 f xbnorm (memset 0)
#define OFF_ISLOTS (OFF_SLOTS + 256)              // 256 f info   (memset 0)
#define OFF_RS     (OFF_ISLOTS + 256)             // 100001 ints
#define OFF_NEXT   (OFF_RS + BN + 1)              // 100000 ints
#define OFF_EQ     ((OFF_NEXT + BN + 1) & ~(size_t)1)  // int2[EN], 8B-aligned
#define OFF_BS     (OFF_EQ + 2 * (size_t)EN)      // 128 ints

typedef __attribute__((ext_vector_type(8))) short short8;      // 8 bf16 = 4 VGPR
typedef __attribute__((ext_vector_type(16))) float f32x16;     // MFMA 32x32 acc

// split fp32 -> bf16 hi (truncate) + bf16 lo (RNE of residual); pack pairs.
// element order: x0 -> low 16 bits (k even), x1 -> high 16 bits (k odd).
__device__ __forceinline__ void split2(float x0, float x1, unsigned& hi, unsigned& lo) {
    const unsigned b0 = __float_as_uint(x0), b1 = __float_as_uint(x1);
    const unsigned h0 = b0 & 0xFFFF0000u, h1 = b1 & 0xFFFF0000u;
    hi = (h0 >> 16) | h1;
    const float r0 = x0 - __uint_as_float(h0);
    const float r1 = x1 - __uint_as_float(h1);
    unsigned c0 = __float_as_uint(r0), c1 = __float_as_uint(r1);
    c0 += 0x7FFFu + ((c0 >> 16) & 1u);
    c1 += 0x7FFFu + ((c1 >> 16) & 1u);
    lo = (c0 >> 16) | (c1 & 0xFFFF0000u);
}

// ---------------- GEMM via split-bf16 MFMA: h = [X_B; codebook*warm] @ W
// + fused xb_norm + fused dst-histogram in tail blocks.
// W (128x128 fp32) is pre-packed per block into LDS as hi/lo bf16 B-fragments
// for v_mfma_f32_32x32x16_bf16 (B: col=lane&31, k=(lane>>5)*8+j). K-loop is
// barrier-free: A is loaded fp32 from global, split to hi/lo in registers.
// 4-term product (hi*hi + lo*hi + hi*lo + lo*lo) => ~2^-17 relative error.
__launch_bounds__(256, 2)
__global__ void k_gemm(const float* __restrict__ X_B, const float* __restrict__ codebook,
                       const float* __restrict__ W, const float* __restrict__ warm,
                       float* __restrict__ h, float* __restrict__ slots,
                       const int* __restrict__ edge_dst, int* __restrict__ cnt) {
    if (blockIdx.x >= GEMM_NB) {
        // ---- histogram by dst (int4), block-uniform branch, no barriers ----
        const int e4 = (blockIdx.x - GEMM_NB) * 256 + threadIdx.x;
        if (e4 < EN / 4) {
            const int4 d = ((const int4*)edge_dst)[e4];
            atomicAdd(&cnt[d.x], 1);
            atomicAdd(&cnt[d.y], 1);
            atomicAdd(&cnt[d.z], 1);
            atomicAdd(&cnt[d.w], 1);
        }
        return;
    }

    // Wp[half][ks][ct][lane] : half 0=hi,1=lo; ks=K/16 step; ct=32-col tile
    __shared__ short8 Wp[2 * 8 * 4 * 64];   // 64 KB

    const int tid = threadIdx.x;
    const float wu = *warm;

    // ---- pack W into B-fragment layout (once per block, coalesced reads) ----
#pragma unroll
    for (int i = 0; i < 8; i++) {
        const int c = tid + i * 256;          // 0..2047 = (ks, ct, lane)
        const int lane_c = c & 63;
        const int ct_c = (c >> 6) & 3;
        const int ks_c = (c >> 8) & 7;
        const int col = ct_c * 32 + (lane_c & 31);
        const int kb = ks_c * 16 + (lane_c >> 5) * 8;
        union { unsigned u[4]; short8 v; } uh, ul;
#pragma unroll
        for (int j2 = 0; j2 < 4; j2++) {
            const float x0 = W[(size_t)(kb + 2 * j2) * DD + col];
            const float x1 = W[(size_t)(kb + 2 * j2 + 1) * DD + col];
            split2(x0, x1, uh.u[j2], ul.u[j2]);
        }
        Wp[((0 * 8 + ks_c) * 4 + ct_c) * 64 + lane_c] = uh.v;
        Wp[((1 * 8 + ks_c) * 4 + ct_c) * 64 + lane_c] = ul.v;
    }
    __syncthreads();

    // ---- per-wave 32-row x 128-col tile ----
    const int lane = tid & 63;
    const int w = tid >> 6;
    const int r0 = blockIdx.x * MT;
    const int rw0 = r0 + w * 32;
    const int rr = lane & 31;
    const int kh = lane >> 5;
    const int row = rw0 + rr;

    // source row pointer + scale (codebook rows scaled by warm; OOB rows -> 0)
    const bool is_x = (row < BN);
    const bool valid = (row < NROWS);
    const float* src = is_x ? (X_B + (size_t)row * DD)
                            : (codebook + (size_t)(valid ? (row - BN) : 0) * DD);
    const float scale = is_x ? 1.f : (valid ? wu : 0.f);

    f32x16 acc0 = {}, acc1 = {}, acc2 = {}, acc3 = {};
    float ss = 0.f;   // xb_norm partial (this lane's k-half of its row)

#pragma unroll
    for (int ks = 0; ks < 8; ks++) {
        const float* s = src + ks * 16 + kh * 8;
        float4 q0 = *(const float4*)(s);
        float4 q1 = *(const float4*)(s + 4);
        q0.x *= scale; q0.y *= scale; q0.z *= scale; q0.w *= scale;
        q1.x *= scale; q1.y *= scale; q1.z *= scale; q1.w *= scale;
        ss += q0.x * q0.x + q0.y * q0.y + q0.z * q0.z + q0.w * q0.w +
              q1.x * q1.x + q1.y * q1.y + q1.z * q1.z + q1.w * q1.w;

        union { unsigned u[4]; short8 v; } ah, al;
        split2(q0.x, q0.y, ah.u[0], al.u[0]);
        split2(q0.z, q0.w, ah.u[1], al.u[1]);
        split2(q1.x, q1.y, ah.u[2], al.u[2]);
        split2(q1.z, q1.w, ah.u[3], al.u[3]);

        const short8 bh0 = Wp[((0 * 8 + ks) * 4 + 0) * 64 + lane];
        const short8 bh1 = Wp[((0 * 8 + ks) * 4 + 1) * 64 + lane];
        const short8 bh2 = Wp[((0 * 8 + ks) * 4 + 2) * 64 + lane];
        const short8 bh3 = Wp[((0 * 8 + ks) * 4 + 3) * 64 + lane];
        const short8 bl0 = Wp[((1 * 8 + ks) * 4 + 0) * 64 + lane];
        const short8 bl1 = Wp[((1 * 8 + ks) * 4 + 1) * 64 + lane];
        const short8 bl2 = Wp[((1 * 8 + ks) * 4 + 2) * 64 + lane];
        const short8 bl3 = Wp[((1 * 8 + ks) * 4 + 3) * 64 + lane];

        acc0 = __builtin_amdgcn_mfma_f32_32x32x16_bf16(ah.v, bh0, acc0, 0, 0, 0);
        acc1 = __builtin_amdgcn_mfma_f32_32x32x16_bf16(ah.v, bh1, acc1, 0, 0, 0);
        acc2 = __builtin_amdgcn_mfma_f32_32x32x16_bf16(ah.v, bh2, acc2, 0, 0, 0);
        acc3 = __builtin_amdgcn_mfma_f32_32x32x16_bf16(ah.v, bh3, acc3, 0, 0, 0);
        acc0 = __builtin_amdgcn_mfma_f32_32x32x16_bf16(al.v, bh0, acc0, 0, 0, 0);
        acc1 = __builtin_amdgcn_mfma_f32_32x32x16_bf16(al.v, bh1, acc1, 0, 0, 0);
        acc2 = __builtin_amdgcn_mfma_f32_32x32x16_bf16(al.v, bh2, acc2, 0, 0, 0);
        acc3 = __builtin_amdgcn_mfma_f32_32x32x16_bf16(al.v, bh3, acc3, 0, 0, 0);
        acc0 = __builtin_amdgcn_mfma_f32_32x32x16_bf16(ah.v, bl0, acc0, 0, 0, 0);
        acc1 = __builtin_amdgcn_mfma_f32_32x32x16_bf16(ah.v, bl1, acc1, 0, 0, 0);
        acc2 = __builtin_amdgcn_mfma_f32_32x32x16_bf16(ah.v, bl2, acc2, 0, 0, 0);
        acc3 = __builtin_amdgcn_mfma_f32_32x32x16_bf16(ah.v, bl3, acc3, 0, 0, 0);
        acc0 = __builtin_amdgcn_mfma_f32_32x32x16_bf16(al.v, bl0, acc0, 0, 0, 0);
        acc1 = __builtin_amdgcn_mfma_f32_32x32x16_bf16(al.v, bl1, acc1, 0, 0, 0);
        acc2 = __builtin_amdgcn_mfma_f32_32x32x16_bf16(al.v, bl2, acc2, 0, 0, 0);
        acc3 = __builtin_amdgcn_mfma_f32_32x32x16_bf16(al.v, bl3, acc3, 0, 0, 0);
    }

    // ---- store C: D layout col=lane&31, row=(reg&3)+8*(reg>>2)+4*(lane>>5) ----
    const int colbase = lane & 31;
    const int mbase = 4 * (lane >> 5);
    const bool fullblk = (r0 + MT <= NROWS);
    if (fullblk) {
#pragma unroll
        for (int r = 0; r < 16; r++) {
            const int m = (r & 3) + 8 * (r >> 2) + mbase;
            float* hp = &h[(size_t)(rw0 + m) * DD + colbase];
            hp[0]  = acc0[r];
            hp[32] = acc1[r];
            hp[64] = acc2[r];
            hp[96] = acc3[r];
        }
    } else {
#pragma unroll
        for (int r = 0; r < 16; r++) {
            const int m = (r & 3) + 8 * (r >> 2) + mbase;
            if (rw0 + m < NROWS) {
                float* hp = &h[(size_t)(rw0 + m) * DD + colbase];
                hp[0]  = acc0[r];
                hp[32] = acc1[r];
                hp[64] = acc2[r];
                hp[96] = acc3[r];
            }
        }
    }

    // ---- xb_norm: combine the two k-halves of each row, sqrt, reduce ----
    float p = ss + __shfl_xor(ss, 32);      // full row sum-of-squares
    float local = 0.f;
    if (lane < 32 && row < BN) local = sqrtf(p);
#pragma unroll
    for (int off = 32; off > 0; off >>= 1) local += __shfl_down(local, off);
    if (lane == 0) unsafeAtomicAdd(&slots[blockIdx.x & 255], local);
}

// ---------------- scan phase 1 ----------------
__launch_bounds__(1024)
__global__ void k_scan1(const int* __restrict__ cnt, int* __restrict__ rs,
                        int* __restrict__ bs) {
    __shared__ int sd[1024];
    const int t = threadIdx.x;
    const int i = blockIdx.x * 1024 + t;
    int v = (i < BN) ? cnt[i] : 0;
    sd[t] = v;
    __syncthreads();
    for (int off = 1; off < 1024; off <<= 1) {
        int x = (t >= off) ? sd[t - off] : 0;
        __syncthreads();
        sd[t] += x;
        __syncthreads();
    }
    if (i < BN) rs[i] = sd[t] - v;
    if (t == 0) bs[blockIdx.x] = sd[1023];
}

// ---------------- scan phase 2 ----------------
__global__ void k_scan2(int* __restrict__ bs) {
    __shared__ int sd[128];
    const int t = threadIdx.x;
    int v = (t < 98) ? bs[t] : 0;
    sd[t] = v;
    __syncthreads();
    for (int off = 1; off < 128; off <<= 1) {
        int x = (t >= off) ? sd[t - off] : 0;
        __syncthreads();
        sd[t] += x;
        __syncthreads();
    }
    bs[t] = sd[t] - v;
}

// ---------------- scan phase 3 ----------------
__launch_bounds__(1024)
__global__ void k_scan3(int* __restrict__ rs, int* __restrict__ next,
                        const int* __restrict__ bs) {
    const int i = blockIdx.x * 1024 + threadIdx.x;
    if (i < BN) {
        int v = rs[i] + bs[blockIdx.x];
        rs[i] = v;
        next[i] = v;
    }
    if (i == 0) rs[BN] = EN;
}

// ---------------- slot-scatter edges into CSR order (packed int2) --------
__global__ void k_slot(const int* __restrict__ edge_dst, const int* __restrict__ edge_src,
                       const float* __restrict__ ew, const int* __restrict__ cidx,
                       int* __restrict__ next, int2* __restrict__ eq) {
    for (int e = blockIdx.x * blockDim.x + threadIdx.x; e < EN;
         e += gridDim.x * blockDim.x) {
        const int d = edge_dst[e];
        const int s = edge_src[e];
        const int p = atomicAdd(&next[d], 1);
        const int se = (s < BN) ? s : (BN + cidx[s]);
        eq[p] = make_int2(se, __float_as_int(ew[e]));
    }
}

// ---------------- fused aggregate + info ----------------
__launch_bounds__(256)
__global__ void k_aggregate(const float* __restrict__ h, const int* __restrict__ rs,
                            const int2* __restrict__ eq,
                            const float* __restrict__ b, const float* __restrict__ grad,
                            float* __restrict__ out, float* __restrict__ islots) {
    const int lane = threadIdx.x & 63;
    const int wave = threadIdx.x >> 6;
    const int row = blockIdx.x * 4 + wave;   // grid 25000
    const float2* h2 = (const float2*)h;
    const float2* g2 = (const float2*)grad;

    float myinfo = 0.f;
    {
        const int gid = blockIdx.x * 256 + threadIdx.x;
        if (gid < NM * DD) myinfo = b[gid & 127] * grad[gid];
    }

    const int s0 = rs[row], s1 = rs[row + 1];
    const int cnt = s1 - s0;

    const float2 hd = h2[(size_t)row * 64 + lane];
    float2 acc = ((const float2*)b)[lane];
    int sv = 0; float wv = 0.f;
    if (lane < cnt) {
        const int2 e = eq[s0 + lane];
        sv = e.x; wv = __int_as_float(e.y);
    }

    float2 gacc = make_float2(0.f, 0.f);
    const int nb = (cnt < 64) ? cnt : 64;
    int i = 0;
    for (; i + 4 <= nb; i += 4) {
        const int sr0 = __shfl(sv, i),     sr1 = __shfl(sv, i + 1);
        const int sr2 = __shfl(sv, i + 2), sr3 = __shfl(sv, i + 3);
        const float w0 = __shfl(wv, i),     w1 = __shfl(wv, i + 1);
        const float w2 = __shfl(wv, i + 2), w3 = __shfl(wv, i + 3);
        const float2 h0 = h2[(size_t)sr0 * 64 + lane];
        const float2 h1 = h2[(size_t)sr1 * 64 + lane];
        const float2 hh2 = h2[(size_t)sr2 * 64 + lane];
        const float2 h3 = h2[(size_t)sr3 * 64 + lane];
        const int m0 = sr0 - BN, m1 = sr1 - BN, m2 = sr2 - BN, m3 = sr3 - BN;
        const float2 g0 = g2[(size_t)max(m0, 0) * 64 + lane];
        const float2 g1 = g2[(size_t)max(m1, 0) * 64 + lane];
        const float2 g2v = g2[(size_t)max(m2, 0) * 64 + lane];
        const float2 g3 = g2[(size_t)max(m3, 0) * 64 + lane];
        acc.x += w0 * h0.x + w1 * h1.x + w2 * hh2.x + w3 * h3.x;
        acc.y += w0 * h0.y + w1 * h1.y + w2 * hh2.y + w3 * h3.y;
        const float gw0 = (m0 >= 0) ? w0 : 0.f, gw1 = (m1 >= 0) ? w1 : 0.f;
        const float gw2 = (m2 >= 0) ? w2 : 0.f, gw3 = (m3 >= 0) ? w3 : 0.f;
        gacc.x += gw0 * g0.x + gw1 * g1.x + gw2 * g2v.x + gw3 * g3.x;
        gacc.y += gw0 * g0.y + gw1 * g1.y + gw2 * g2v.y + gw3 * g3.y;
    }
    for (; i < nb; i++) {
        const int sr = __shfl(sv, i);
        const float w = __shfl(wv, i);
        const float2 hv = h2[(size_t)sr * 64 + lane];
        acc.x += w * hv.x; acc.y += w * hv.y;
        const int m = sr - BN;
        const float2 gv = g2[(size_t)max(m, 0) * 64 + lane];
        const float gw = (m >= 0) ? w : 0.f;
        gacc.x += gw * gv.x; gacc.y += gw * gv.y;
    }
    for (int j = s0 + 64; j < s1; j++) {
        const int2 e = eq[j];
        const int sr = e.x; const float w = __int_as_float(e.y);
        const float2 hv = h2[(size_t)sr * 64 + lane];
        acc.x += w * hv.x; acc.y += w * hv.y;
        const int m = sr - BN;
        const float2 gv = g2[(size_t)max(m, 0) * 64 + lane];
        const float gw = (m >= 0) ? w : 0.f;
        gacc.x += gw * gv.x; gacc.y += gw * gv.y;
    }

    ((float2*)out)[(size_t)row * 64 + lane] = acc;
    myinfo += hd.x * gacc.x + hd.y * gacc.y;
#pragma unroll
    for (int off = 32; off > 0; off >>= 1) myinfo += __shfl_down(myinfo, off);
    __shared__ float li[4];
    if (lane == 0) li[wave] = myinfo;
    __syncthreads();
    if (threadIdx.x == 0)
        unsafeAtomicAdd(&islots[blockIdx.x & 255], li[0] + li[1] + li[2] + li[3]);
}

// ---------------- finalize scalars ----------------
__global__ void k_finalize(const float* __restrict__ slots, const float* __restrict__ islots,
                           const float* __restrict__ warm, float* __restrict__ out_tail) {
    float v = slots[threadIdx.x];
    float u = islots[threadIdx.x];
#pragma unroll
    for (int off = 32; off > 0; off >>= 1) {
        v += __shfl_down(v, off);
        u += __shfl_down(u, off);
    }
    __shared__ float lv[4], lu[4];
    if ((threadIdx.x & 63) == 0) { lv[threadIdx.x >> 6] = v; lu[threadIdx.x >> 6] = u; }
    __syncthreads();
    if (threadIdx.x == 0) {
        out_tail[0] = (lv[0] + lv[1] + lv[2] + lv[3]) / (float)BN;
        out_tail[1] = (lu[0] + lu[1] + lu[2] + lu[3]) * warm[0];
    }
}

extern "C" void kernel_launch(void* const* d_in, const int* in_sizes, int n_in,
                              void* d_out, int out_size, void* d_ws, size_t ws_size,
                              hipStream_t stream) {
    const float* X_B      = (const float*)d_in[0];
    const int*   edge_dst = (const int*)d_in[1];
    const int*   edge_src = (const int*)d_in[2];
    const float* ew       = (const float*)d_in[3];
    const int*   cidx     = (const int*)d_in[5];
    const float* codebook = (const float*)d_in[6];
    const float* grad     = (const float*)d_in[7];
    const float* W        = (const float*)d_in[8];
    const float* b        = (const float*)d_in[9];
    const float* warm     = (const float*)d_in[10];
    float* out = (float*)d_out;
    float* ws  = (float*)d_ws;

    float* h      = ws + OFF_H;
    int*   cnt    = (int*)(ws + OFF_CNT);
    float* slots  = ws + OFF_SLOTS;
    float* islots = ws + OFF_ISLOTS;
    int*   rs     = (int*)(ws + OFF_RS);
    int*   next   = (int*)(ws + OFF_NEXT);
    int2*  eq     = (int2*)(ws + OFF_EQ);
    int*   bs     = (int*)(ws + OFF_BS);

    hipMemsetAsync(cnt, 0, (BN + 512) * sizeof(float), stream);

    k_gemm<<<GEMM_NB + HIST_NB, 256, 0, stream>>>(X_B, codebook, W, warm, h, slots,
                                                  edge_dst, cnt);
    k_scan1<<<98, 1024, 0, stream>>>(cnt, rs, bs);
    k_scan2<<<1, 128, 0, stream>>>(bs);
    k_scan3<<<98, 1024, 0, stream>>>(rs, next, bs);
    k_slot<<<512, 256, 0, stream>>>(edge_dst, edge_src, ew, cidx, next, eq);
    k_aggregate<<<BN / 4, 256, 0, stream>>>(h, rs, eq, b, grad, out, islots);
    k_finalize<<<1, 256, 0, stream>>>(slots, islots, warm, out + (size_t)BN * DD);
}

// Round 4
// 231.094 us; speedup vs baseline: 1.1794x; 1.0326x over previous
//
#include <hip/hip_runtime.h>

#define BN 100000
#define DD 128
#define EN 500000
#define NM 4096
#define NROWS (BN + NM)     // 104096
#define MT 128              // gemm row tile
#define GEMM_NB ((NROWS + MT - 1) / MT)   // 814 gemm blocks
#define HIST_NB ((EN / 4 + 255) / 256)    // 489 hist blocks

// ---- ws layout (4-byte units) ----
#define OFF_H      0
#define LEN_H      ((size_t)NROWS * DD)           // 13,324,288
#define OFF_CNT    (LEN_H)                        // 100000 ints  (memset 0)
#define OFF_SLOTS  (OFF_CNT + BN)                 // 256 f xbnorm (memset 0)
#define OFF_ISLOTS (OFF_SLOTS + 256)              // 256 f info   (memset 0)
#define OFF_RS     (OFF_ISLOTS + 256)             // 100001 ints
#define OFF_NEXT   (OFF_RS + BN + 1)              // 100000 ints
#define OFF_EQ     ((OFF_NEXT + BN + 1) & ~(size_t)1)  // int2[EN], 8B-aligned
#define OFF_BS     (OFF_EQ + 2 * (size_t)EN)      // 128 ints

typedef __attribute__((ext_vector_type(8))) short short8;      // 8 bf16 = 4 VGPR
typedef __attribute__((ext_vector_type(16))) float f32x16;     // MFMA 32x32 acc

// split fp32 -> bf16 hi (truncate) + bf16 lo (RNE of residual); pack pairs.
// element order: x0 -> low 16 bits (k even), x1 -> high 16 bits (k odd).
__device__ __forceinline__ void split2(float x0, float x1, unsigned& hi, unsigned& lo) {
    const unsigned b0 = __float_as_uint(x0), b1 = __float_as_uint(x1);
    const unsigned h0 = b0 & 0xFFFF0000u, h1 = b1 & 0xFFFF0000u;
    hi = (h0 >> 16) | h1;
    const float r0 = x0 - __uint_as_float(h0);
    const float r1 = x1 - __uint_as_float(h1);
    unsigned c0 = __float_as_uint(r0), c1 = __float_as_uint(r1);
    c0 += 0x7FFFu + ((c0 >> 16) & 1u);
    c1 += 0x7FFFu + ((c1 >> 16) & 1u);
    lo = (c0 >> 16) | (c1 & 0xFFFF0000u);
}

// ---------------- GEMM via split-bf16 MFMA: h = [X_B; codebook*warm] @ W
// + fused xb_norm + fused dst-histogram in tail blocks.
__launch_bounds__(256, 2)
__global__ void k_gemm(const float* __restrict__ X_B, const float* __restrict__ codebook,
                       const float* __restrict__ W, const float* __restrict__ warm,
                       float* __restrict__ h, float* __restrict__ slots,
                       const int* __restrict__ edge_dst, int* __restrict__ cnt) {
    if (blockIdx.x >= GEMM_NB) {
        // ---- histogram by dst (int4), block-uniform branch, no barriers ----
        const int e4 = (blockIdx.x - GEMM_NB) * 256 + threadIdx.x;
        if (e4 < EN / 4) {
            const int4 d = ((const int4*)edge_dst)[e4];
            atomicAdd(&cnt[d.x], 1);
            atomicAdd(&cnt[d.y], 1);
            atomicAdd(&cnt[d.z], 1);
            atomicAdd(&cnt[d.w], 1);
        }
        return;
    }

    // Wp[half][ks][ct][lane] : half 0=hi,1=lo; ks=K/16 step; ct=32-col tile
    __shared__ short8 Wp[2 * 8 * 4 * 64];   // 64 KB

    const int tid = threadIdx.x;
    const float wu = *warm;

    // ---- pack W into B-fragment layout (once per block, coalesced reads) ----
#pragma unroll
    for (int i = 0; i < 8; i++) {
        const int c = tid + i * 256;          // 0..2047 = (ks, ct, lane)
        const int lane_c = c & 63;
        const int ct_c = (c >> 6) & 3;
        const int ks_c = (c >> 8) & 7;
        const int col = ct_c * 32 + (lane_c & 31);
        const int kb = ks_c * 16 + (lane_c >> 5) * 8;
        union { unsigned u[4]; short8 v; } uh, ul;
#pragma unroll
        for (int j2 = 0; j2 < 4; j2++) {
            const float x0 = W[(size_t)(kb + 2 * j2) * DD + col];
            const float x1 = W[(size_t)(kb + 2 * j2 + 1) * DD + col];
            split2(x0, x1, uh.u[j2], ul.u[j2]);
        }
        Wp[((0 * 8 + ks_c) * 4 + ct_c) * 64 + lane_c] = uh.v;
        Wp[((1 * 8 + ks_c) * 4 + ct_c) * 64 + lane_c] = ul.v;
    }
    __syncthreads();

    // ---- per-wave 32-row x 128-col tile ----
    const int lane = tid & 63;
    const int w = tid >> 6;
    const int r0 = blockIdx.x * MT;
    const int rw0 = r0 + w * 32;
    const int rr = lane & 31;
    const int kh = lane >> 5;
    const int row = rw0 + rr;

    // source row pointer + scale (codebook rows scaled by warm; OOB rows -> 0)
    const bool is_x = (row < BN);
    const bool valid = (row < NROWS);
    const float* src = is_x ? (X_B + (size_t)row * DD)
                            : (codebook + (size_t)(valid ? (row - BN) : 0) * DD);
    const float scale = is_x ? 1.f : (valid ? wu : 0.f);

    f32x16 acc0 = {}, acc1 = {}, acc2 = {}, acc3 = {};
    float ss = 0.f;   // xb_norm partial (this lane's k-half of its row)

#pragma unroll
    for (int ks = 0; ks < 8; ks++) {
        const float* s = src + ks * 16 + kh * 8;
        float4 q0 = *(const float4*)(s);
        float4 q1 = *(const float4*)(s + 4);
        q0.x *= scale; q0.y *= scale; q0.z *= scale; q0.w *= scale;
        q1.x *= scale; q1.y *= scale; q1.z *= scale; q1.w *= scale;
        ss += q0.x * q0.x + q0.y * q0.y + q0.z * q0.z + q0.w * q0.w +
              q1.x * q1.x + q1.y * q1.y + q1.z * q1.z + q1.w * q1.w;

        union { unsigned u[4]; short8 v; } ah, al;
        split2(q0.x, q0.y, ah.u[0], al.u[0]);
        split2(q0.z, q0.w, ah.u[1], al.u[1]);
        split2(q1.x, q1.y, ah.u[2], al.u[2]);
        split2(q1.z, q1.w, ah.u[3], al.u[3]);

        const short8 bh0 = Wp[((0 * 8 + ks) * 4 + 0) * 64 + lane];
        const short8 bh1 = Wp[((0 * 8 + ks) * 4 + 1) * 64 + lane];
        const short8 bh2 = Wp[((0 * 8 + ks) * 4 + 2) * 64 + lane];
        const short8 bh3 = Wp[((0 * 8 + ks) * 4 + 3) * 64 + lane];
        const short8 bl0 = Wp[((1 * 8 + ks) * 4 + 0) * 64 + lane];
        const short8 bl1 = Wp[((1 * 8 + ks) * 4 + 1) * 64 + lane];
        const short8 bl2 = Wp[((1 * 8 + ks) * 4 + 2) * 64 + lane];
        const short8 bl3 = Wp[((1 * 8 + ks) * 4 + 3) * 64 + lane];

        acc0 = __builtin_amdgcn_mfma_f32_32x32x16_bf16(ah.v, bh0, acc0, 0, 0, 0);
        acc1 = __builtin_amdgcn_mfma_f32_32x32x16_bf16(ah.v, bh1, acc1, 0, 0, 0);
        acc2 = __builtin_amdgcn_mfma_f32_32x32x16_bf16(ah.v, bh2, acc2, 0, 0, 0);
        acc3 = __builtin_amdgcn_mfma_f32_32x32x16_bf16(ah.v, bh3, acc3, 0, 0, 0);
        acc0 = __builtin_amdgcn_mfma_f32_32x32x16_bf16(al.v, bh0, acc0, 0, 0, 0);
        acc1 = __builtin_amdgcn_mfma_f32_32x32x16_bf16(al.v, bh1, acc1, 0, 0, 0);
        acc2 = __builtin_amdgcn_mfma_f32_32x32x16_bf16(al.v, bh2, acc2, 0, 0, 0);
        acc3 = __builtin_amdgcn_mfma_f32_32x32x16_bf16(al.v, bh3, acc3, 0, 0, 0);
        acc0 = __builtin_amdgcn_mfma_f32_32x32x16_bf16(ah.v, bl0, acc0, 0, 0, 0);
        acc1 = __builtin_amdgcn_mfma_f32_32x32x16_bf16(ah.v, bl1, acc1, 0, 0, 0);
        acc2 = __builtin_amdgcn_mfma_f32_32x32x16_bf16(ah.v, bl2, acc2, 0, 0, 0);
        acc3 = __builtin_amdgcn_mfma_f32_32x32x16_bf16(ah.v, bl3, acc3, 0, 0, 0);
        acc0 = __builtin_amdgcn_mfma_f32_32x32x16_bf16(al.v, bl0, acc0, 0, 0, 0);
        acc1 = __builtin_amdgcn_mfma_f32_32x32x16_bf16(al.v, bl1, acc1, 0, 0, 0);
        acc2 = __builtin_amdgcn_mfma_f32_32x32x16_bf16(al.v, bl2, acc2, 0, 0, 0);
        acc3 = __builtin_amdgcn_mfma_f32_32x32x16_bf16(al.v, bl3, acc3, 0, 0, 0);
    }

    // ---- store C: D layout col=lane&31, row=(reg&3)+8*(reg>>2)+4*(lane>>5) ----
    const int colbase = lane & 31;
    const int mbase = 4 * (lane >> 5);
    const bool fullblk = (r0 + MT <= NROWS);
    if (fullblk) {
#pragma unroll
        for (int r = 0; r < 16; r++) {
            const int m = (r & 3) + 8 * (r >> 2) + mbase;
            float* hp = &h[(size_t)(rw0 + m) * DD + colbase];
            hp[0]  = acc0[r];
            hp[32] = acc1[r];
            hp[64] = acc2[r];
            hp[96] = acc3[r];
        }
    } else {
#pragma unroll
        for (int r = 0; r < 16; r++) {
            const int m = (r & 3) + 8 * (r >> 2) + mbase;
            if (rw0 + m < NROWS) {
                float* hp = &h[(size_t)(rw0 + m) * DD + colbase];
                hp[0]  = acc0[r];
                hp[32] = acc1[r];
                hp[64] = acc2[r];
                hp[96] = acc3[r];
            }
        }
    }

    // ---- xb_norm: combine the two k-halves of each row, sqrt, reduce ----
    float p = ss + __shfl_xor(ss, 32);      // full row sum-of-squares
    float local = 0.f;
    if (lane < 32 && row < BN) local = sqrtf(p);
#pragma unroll
    for (int off = 32; off > 0; off >>= 1) local += __shfl_down(local, off);
    if (lane == 0) unsafeAtomicAdd(&slots[blockIdx.x & 255], local);
}

// ---------------- scan phase 1 ----------------
__launch_bounds__(1024)
__global__ void k_scan1(const int* __restrict__ cnt, int* __restrict__ rs,
                        int* __restrict__ bs) {
    __shared__ int sd[1024];
    const int t = threadIdx.x;
    const int i = blockIdx.x * 1024 + t;
    int v = (i < BN) ? cnt[i] : 0;
    sd[t] = v;
    __syncthreads();
    for (int off = 1; off < 1024; off <<= 1) {
        int x = (t >= off) ? sd[t - off] : 0;
        __syncthreads();
        sd[t] += x;
        __syncthreads();
    }
    if (i < BN) rs[i] = sd[t] - v;
    if (t == 0) bs[blockIdx.x] = sd[1023];
}

// ---------------- scan phase 2 ----------------
__global__ void k_scan2(int* __restrict__ bs) {
    __shared__ int sd[128];
    const int t = threadIdx.x;
    int v = (t < 98) ? bs[t] : 0;
    sd[t] = v;
    __syncthreads();
    for (int off = 1; off < 128; off <<= 1) {
        int x = (t >= off) ? sd[t - off] : 0;
        __syncthreads();
        sd[t] += x;
        __syncthreads();
    }
    bs[t] = sd[t] - v;
}

// ---------------- scan phase 3 ----------------
__launch_bounds__(1024)
__global__ void k_scan3(int* __restrict__ rs, int* __restrict__ next,
                        const int* __restrict__ bs) {
    const int i = blockIdx.x * 1024 + threadIdx.x;
    if (i < BN) {
        int v = rs[i] + bs[blockIdx.x];
        rs[i] = v;
        next[i] = v;
    }
    if (i == 0) rs[BN] = EN;
}

// ---------------- slot-scatter edges into CSR order (packed int2) --------
__global__ void k_slot(const int* __restrict__ edge_dst, const int* __restrict__ edge_src,
                       const float* __restrict__ ew, const int* __restrict__ cidx,
                       int* __restrict__ next, int2* __restrict__ eq) {
    for (int e = blockIdx.x * blockDim.x + threadIdx.x; e < EN;
         e += gridDim.x * blockDim.x) {
        const int d = edge_dst[e];
        const int s = edge_src[e];
        const int p = atomicAdd(&next[d], 1);
        const int se = (s < BN) ? s : (BN + cidx[s]);
        eq[p] = make_int2(se, __float_as_int(ew[e]));
    }
}

// ---------------- fused aggregate + info ----------------
// 2 rows per wave (32-lane groups), float4 per lane: 2 independent edge
// chains + 4-deep unroll => 16 concurrent gathers/wave (2x MLP vs float2).
__launch_bounds__(256)
__global__ void k_aggregate(const float* __restrict__ h, const int* __restrict__ rs,
                            const int2* __restrict__ eq,
                            const float* __restrict__ b, const float* __restrict__ grad,
                            float* __restrict__ out, float* __restrict__ islots) {
    const int lane = threadIdx.x & 63;
    const int wave = threadIdx.x >> 6;
    const int grp  = lane >> 5;              // 0/1: which row of this wave
    const int l    = lane & 31;              // lane within 32-lane group
    const int gb   = grp << 5;               // group base lane (for shfl)
    const int row  = blockIdx.x * 8 + wave * 2 + grp;   // grid 12500
    const float4* h4 = (const float4*)h;
    const float4* g4 = (const float4*)grad;

    float myinfo = 0.f;
    {
        const int gid = blockIdx.x * 256 + threadIdx.x;
        if (gid < NM * DD) myinfo = b[gid & 127] * grad[gid];
    }

    const int s0 = rs[row], s1 = rs[row + 1];
    const int cnt = s1 - s0;

    const float4 hd = h4[(size_t)row * 32 + l];
    float4 acc = ((const float4*)b)[l];
    int sv = 0; float wv = 0.f;
    if (l < cnt) {
        const int2 e = eq[s0 + l];
        sv = e.x; wv = __int_as_float(e.y);
    }

    float4 gacc = make_float4(0.f, 0.f, 0.f, 0.f);
    const int nb = (cnt < 32) ? cnt : 32;
    int i = 0;
    for (; i + 4 <= nb; i += 4) {
        const int sr0 = __shfl(sv, gb + i),     sr1 = __shfl(sv, gb + i + 1);
        const int sr2 = __shfl(sv, gb + i + 2), sr3 = __shfl(sv, gb + i + 3);
        const float w0 = __shfl(wv, gb + i),     w1 = __shfl(wv, gb + i + 1);
        const float w2 = __shfl(wv, gb + i + 2), w3 = __shfl(wv, gb + i + 3);
        const float4 h0 = h4[(size_t)sr0 * 32 + l];
        const float4 h1 = h4[(size_t)sr1 * 32 + l];
        const float4 hv2 = h4[(size_t)sr2 * 32 + l];
        const float4 h3 = h4[(size_t)sr3 * 32 + l];
        const int m0 = sr0 - BN, m1 = sr1 - BN, m2 = sr2 - BN, m3 = sr3 - BN;
        const float4 g0 = g4[(size_t)max(m0, 0) * 32 + l];
        const float4 g1 = g4[(size_t)max(m1, 0) * 32 + l];
        const float4 gv2 = g4[(size_t)max(m2, 0) * 32 + l];
        const float4 g3 = g4[(size_t)max(m3, 0) * 32 + l];
        acc.x += w0 * h0.x + w1 * h1.x + w2 * hv2.x + w3 * h3.x;
        acc.y += w0 * h0.y + w1 * h1.y + w2 * hv2.y + w3 * h3.y;
        acc.z += w0 * h0.z + w1 * h1.z + w2 * hv2.z + w3 * h3.z;
        acc.w += w0 * h0.w + w1 * h1.w + w2 * hv2.w + w3 * h3.w;
        const float gw0 = (m0 >= 0) ? w0 : 0.f, gw1 = (m1 >= 0) ? w1 : 0.f;
        const float gw2 = (m2 >= 0) ? w2 : 0.f, gw3 = (m3 >= 0) ? w3 : 0.f;
        gacc.x += gw0 * g0.x + gw1 * g1.x + gw2 * gv2.x + gw3 * g3.x;
        gacc.y += gw0 * g0.y + gw1 * g1.y + gw2 * gv2.y + gw3 * g3.y;
        gacc.z += gw0 * g0.z + gw1 * g1.z + gw2 * gv2.z + gw3 * g3.z;
        gacc.w += gw0 * g0.w + gw1 * g1.w + gw2 * gv2.w + gw3 * g3.w;
    }
    for (; i < nb; i++) {
        const int sr = __shfl(sv, gb + i);
        const float w = __shfl(wv, gb + i);
        const float4 hv = h4[(size_t)sr * 32 + l];
        acc.x += w * hv.x; acc.y += w * hv.y; acc.z += w * hv.z; acc.w += w * hv.w;
        const int m = sr - BN;
        const float4 gv = g4[(size_t)max(m, 0) * 32 + l];
        const float gw = (m >= 0) ? w : 0.f;
        gacc.x += gw * gv.x; gacc.y += gw * gv.y; gacc.z += gw * gv.z; gacc.w += gw * gv.w;
    }
    for (int j = s0 + 32; j < s1; j++) {
        const int2 e = eq[j];
        const int sr = e.x; const float w = __int_as_float(e.y);
        const float4 hv = h4[(size_t)sr * 32 + l];
        acc.x += w * hv.x; acc.y += w * hv.y; acc.z += w * hv.z; acc.w += w * hv.w;
        const int m = sr - BN;
        const float4 gv = g4[(size_t)max(m, 0) * 32 + l];
        const float gw = (m >= 0) ? w : 0.f;
        gacc.x += gw * gv.x; gacc.y += gw * gv.y; gacc.z += gw * gv.z; gacc.w += gw * gv.w;
    }

    ((float4*)out)[(size_t)row * 32 + l] = acc;
    myinfo += hd.x * gacc.x + hd.y * gacc.y + hd.z * gacc.z + hd.w * gacc.w;
#pragma unroll
    for (int off = 32; off > 0; off >>= 1) myinfo += __shfl_down(myinfo, off);
    __shared__ float li[4];
    if (lane == 0) li[wave] = myinfo;
    __syncthreads();
    if (threadIdx.x == 0)
        unsafeAtomicAdd(&islots[blockIdx.x & 255], li[0] + li[1] + li[2] + li[3]);
}

// ---------------- finalize scalars ----------------
__global__ void k_finalize(const float* __restrict__ slots, const float* __restrict__ islots,
                           const float* __restrict__ warm, float* __restrict__ out_tail) {
    float v = slots[threadIdx.x];
    float u = islots[threadIdx.x];
#pragma unroll
    for (int off = 32; off > 0; off >>= 1) {
        v += __shfl_down(v, off);
        u += __shfl_down(u, off);
    }
    __shared__ float lv[4], lu[4];
    if ((threadIdx.x & 63) == 0) { lv[threadIdx.x >> 6] = v; lu[threadIdx.x >> 6] = u; }
    __syncthreads();
    if (threadIdx.x == 0) {
        out_tail[0] = (lv[0] + lv[1] + lv[2] + lv[3]) / (float)BN;
        out_tail[1] = (lu[0] + lu[1] + lu[2] + lu[3]) * warm[0];
    }
}

extern "C" void kernel_launch(void* const* d_in, const int* in_sizes, int n_in,
                              void* d_out, int out_size, void* d_ws, size_t ws_size,
                              hipStream_t stream) {
    const float* X_B      = (const float*)d_in[0];
    const int*   edge_dst = (const int*)d_in[1];
    const int*   edge_src = (const int*)d_in[2];
    const float* ew       = (const float*)d_in[3];
    const int*   cidx     = (const int*)d_in[5];
    const float* codebook = (const float*)d_in[6];
    const float* grad     = (const float*)d_in[7];
    const float* W        = (const float*)d_in[8];
    const float* b        = (const float*)d_in[9];
    const float* warm     = (const float*)d_in[10];
    float* out = (float*)d_out;
    float* ws  = (float*)d_ws;

    float* h      = ws + OFF_H;
    int*   cnt    = (int*)(ws + OFF_CNT);
    float* slots  = ws + OFF_SLOTS;
    float* islots = ws + OFF_ISLOTS;
    int*   rs     = (int*)(ws + OFF_RS);
    int*   next   = (int*)(ws + OFF_NEXT);
    int2*  eq     = (int2*)(ws + OFF_EQ);
    int*   bs     = (int*)(ws + OFF_BS);

    hipMemsetAsync(cnt, 0, (BN + 512) * sizeof(float), stream);

    k_gemm<<<GEMM_NB + HIST_NB, 256, 0, stream>>>(X_B, codebook, W, warm, h, slots,
                                                  edge_dst, cnt);
    k_scan1<<<98, 1024, 0, stream>>>(cnt, rs, bs);
    k_scan2<<<1, 128, 0, stream>>>(bs);
    k_scan3<<<98, 1024, 0, stream>>>(rs, next, bs);
    k_slot<<<512, 256, 0, stream>>>(edge_dst, edge_src, ew, cidx, next, eq);
    k_aggregate<<<BN / 8, 256, 0, stream>>>(h, rs, eq, b, grad, out, islots);
    k_finalize<<<1, 256, 0, stream>>>(slots, islots, warm, out + (size_t)BN * DD);
}